// Round 5
// baseline (171.332 us; speedup 1.0000x reference)
//
#include <hip/hip_runtime.h>
#include <math.h>

#define N_NODES 100000
#define N_EDGES 1600000
#define C_IN    128
#define H_DIM   64
#define G_GRAPHS 512
#define MAXG    4096      // max nodes/graph in LDS (mean 195, huge margin)
#define ELCAP   65536     // both-kept edge list cap (expected ~hundreds)
#define KPG     32        // kept-per-graph cap (scores sum to 1, thresh 0.05 -> <=19)
#define NBITS   3136      // ceil(N/32) rounded up

// 64-ary wave-parallel lower_bound over sorted batch (all lanes participate,
// uniform result). ~4 rounds of one cached load each vs 17 serial loads.
__device__ __forceinline__ int lbound64(const int* __restrict__ b, int val, int lane) {
    int lo = 0, hi = N_NODES;
    while (lo < hi) {
        int len = hi - lo;
        if (len <= 64) {
            int p = lo + lane;
            bool c = (p >= hi) || (b[p] >= val);
            unsigned long long bal = __ballot(c);
            lo = (bal == 0ull) ? hi : lo + (__ffsll((long long)bal) - 1);
            hi = lo;
        } else {
            int step = len >> 6;                       // >= 1
            int p = lo + lane * step;                  // all probes < hi
            bool c = b[p] >= val;
            unsigned long long bal = __ballot(c);
            if (bal == 0ull) {
                lo = lo + 63 * step + 1;
            } else {
                int j = __ffsll((long long)bal) - 1;
                if (j == 0) { hi = lo; }
                else { int nlo = lo + (j - 1) * step + 1; hi = lo + j * step; lo = nlo; }
            }
        }
    }
    return lo;
}

// ---------- fused kpre+kA4: block g = graph g (contiguous rows since batch sorted).
// 1024 threads: 16 waves stream x rows -> raw scores in LDS; first 256 threads then
// run the softmax/KL/compaction with kA4's EXACT stride-256 loops and 4-slot
// reduction tree (bitwise-identical z/thresh/s/KL). ----------
__global__ __launch_bounds__(1024, 4) void kSM(
    const float* __restrict__ x, const int* __restrict__ batch,
    const float* __restrict__ attn, const float* __restrict__ pool_w,
    float* __restrict__ sc, unsigned int* __restrict__ kept_bits,
    int* __restrict__ klist, int* __restrict__ kcnt,
    float* __restrict__ B, int* __restrict__ elcount, float* __restrict__ out)
{
    __shared__ float buf[MAXG];   // 16 KB raw->exp scores
    __shared__ float red[4];
    __shared__ int   lst[KPG];
    __shared__ int   cntk;
    const int g = blockIdx.x;
    const int t = threadIdx.x;    // 1024
    const int lane = t & 63;
    const int w64 = t >> 6;       // wave 0..15
    if (g == 0 && t == 0) *elcount = 0;
    if (t == 0) cntk = 0;

    const int ns = lbound64(batch, g, lane);
    const int ne = lbound64(batch, g + 1, lane);
    const int cn = ne - ns;
    if (cn <= 0) {
        if (t == 0) { out[G_GRAPHS + g] = 0.f; kcnt[g] = 0; }
        return;
    }

    // clear this graph's kept_bits range via atomicAnd (bit-disjoint across blocks:
    // node space is partitioned by graph, so no zero-pass kernel is needed)
    {
        const int w0 = ns >> 5, w1 = (ne - 1) >> 5;
        for (int wd = w0 + t; wd <= w1; wd += 1024) {
            int lo_b = ns - (wd << 5); if (lo_b < 0) lo_b = 0;
            int hi_b = ne - (wd << 5); if (hi_b > 32) hi_b = 32;
            unsigned int mask = (hi_b == 32 ? 0xFFFFFFFFu : ((1u << hi_b) - 1u))
                                & ~((1u << lo_b) - 1u);
            atomicAnd(&kept_bits[wd], ~mask);
        }
    }

    // raw scores: each 32-lane half-wave computes one row (math identical to kpre)
    {
        const int l32  = lane & 31;
        const int half = lane >> 5;
        const int hw   = (w64 << 1) + half;   // half-wave id 0..31
        const float4 pwv = ((const float4*)pool_w)[l32];
        for (int r = ns + hw; r < ne; r += 32) {
            float4 xa = ((const float4*)(x + (size_t)r * C_IN))[l32];
            float pa = xa.x * pwv.x + xa.y * pwv.y + xa.z * pwv.z + xa.w * pwv.w;
            #pragma unroll
            for (int m = 16; m > 0; m >>= 1) pa += __shfl_xor(pa, m, 64);
            if (l32 == 0) buf[r - ns] = pa;
        }
    }
    __syncthreads();

    // ---- softmax + threshold + KL + compaction: kA4-identical (first 256 threads) ----
    float lmax = -3.4e38f;
    if (t < 256) for (int i = t; i < cn; i += 256) lmax = fmaxf(lmax, buf[i]);
    #pragma unroll
    for (int m = 32; m > 0; m >>= 1) lmax = fmaxf(lmax, __shfl_xor(lmax, m, 64));
    if (t < 256 && lane == 0) red[w64] = lmax;
    __syncthreads();
    const float mx = fmaxf(fmaxf(red[0], red[1]), fmaxf(red[2], red[3]));
    __syncthreads();

    float lsum = 0.f;
    if (t < 256) for (int i = t; i < cn; i += 256) {
        float e = expf(buf[i] - mx); buf[i] = e; lsum += e;
    }
    #pragma unroll
    for (int m = 32; m > 0; m >>= 1) lsum += __shfl_xor(lsum, m, 64);
    if (t < 256 && lane == 0) red[w64] = lsum;
    __syncthreads();
    const float z = (red[0] + red[1]) + (red[2] + red[3]);
    __syncthreads();

    // smax = exp(m - m)/z = 1/z exactly (same rounding as reference's max(e)/z)
    const float thresh = fminf(1.f / z - 1e-7f, 0.05f);
    float klacc = 0.f;
    if (t < 256) {
        for (int i = t; i < cn; i += 256) {
            float s = buf[i] / z;
            if (s > thresh) {
                int n = ns + i;
                int p = atomicAdd(&cntk, 1);
                if (p < KPG) lst[p] = i;
                sc[n] = s;
                float a = attn[n];
                klacc += a * (logf(a) - logf(s + 1e-14f));
            }
        }
    }
    #pragma unroll
    for (int m = 32; m > 0; m >>= 1) klacc += __shfl_xor(klacc, m, 64);
    if (t < 256 && lane == 0) red[w64] = klacc;
    __syncthreads();                               // also makes cntk/lst visible
    const float klsum = (red[0] + red[1]) + (red[2] + red[3]);
    int kct = cntk;
    int kc = kct < KPG ? kct : KPG;
    if (t == 0) {
        out[G_GRAPHS + g] = (kct > 0) ? klsum / (float)kct : 0.f;
        kcnt[g] = kc;
    }
    for (int i = t; i < kc; i += 1024) {
        int n = ns + lst[i];
        klist[g * KPG + i] = n;
        atomicOr(&kept_bits[n >> 5], 1u << (n & 31));
    }
    for (int j = t; j < kc * H_DIM; j += 1024)
        B[(size_t)(ns + lst[j >> 6]) * H_DIM + (j & 63)] = 0.f;
}

// wave-ballot list emit: one global atomic per wave-with-hits (rare both-kept edges only)
__device__ __forceinline__ void emit(bool hit, int s, int d, int* __restrict__ list,
                                     int cap, int* __restrict__ count, int lane) {
    unsigned long long bal = __ballot(hit);
    if (bal == 0ull) return;
    int leader = __ffsll((long long)bal) - 1;
    int cnt = __popcll(bal);
    int base = 0;
    if (lane == leader) base = atomicAdd(count, cnt);
    base = __shfl(base, leader, 64);
    if (hit) {
        int p = base + __popcll(bal & ((1ull << lane) - 1ull));
        if (p < cap) { list[p] = s; list[cap + p] = d; }
    }
}

// ---------- fused edge scan + layer-1 agg: no W1 LDS staging (W1 is L1/L2-hot) ----------
__global__ void kscan(const int* __restrict__ ei, const unsigned int* __restrict__ bits,
                      const float* __restrict__ x, const float* __restrict__ W1,
                      float* __restrict__ B, int* __restrict__ elsd,
                      int* __restrict__ elcount) {
    __shared__ int ls[1024], ld[1024];    // 8 KB only -> high occupancy
    __shared__ int c1;
    const int t = threadIdx.x;
    const int lane = t & 63;
    if (t == 0) c1 = 0;
    int t4 = blockIdx.x * 256 + t;
    bool valid = t4 < (N_EDGES / 4);
    int4 s4 = make_int4(0, 0, 0, 0), d4 = make_int4(0, 0, 0, 0);
    if (valid) {
        s4 = ((const int4*)ei)[t4];
        d4 = ((const int4*)(ei + N_EDGES))[t4];
    }
    __syncthreads();  // c1 = 0 visible
    int sv[4] = {s4.x, s4.y, s4.z, s4.w};
    int dv[4] = {d4.x, d4.y, d4.z, d4.w};
    bool bk[4];
    #pragma unroll
    for (int q = 0; q < 4; ++q) {
        int ss = sv[q], dd = dv[q];
        bool kd = valid && (((bits[dd >> 5] >> (dd & 31)) & 1u) != 0u);
        bk[q] = kd && (((bits[ss >> 5] >> (ss & 31)) & 1u) != 0u);
        if (kd) { int p = atomicAdd(&c1, 1); ls[p] = ss; ld[p] = dd; }
    }
    #pragma unroll
    for (int q = 0; q < 4; ++q) emit(bk[q], sv[q], dv[q], elsd, ELCAP, elcount, lane);
    __syncthreads();
    const int nloc = c1;
    if (nloc == 0) return;
    const int w = t >> 6;
    for (int idx = w; idx < nloc; idx += 4) {
        int s = ls[idx];
        int d = ld[idx];
        const float4* xr = (const float4*)(x + (size_t)s * C_IN);
        float acc = 0.f;
        #pragma unroll 8
        for (int k4 = 0; k4 < C_IN / 4; ++k4) {
            float4 xv = xr[k4];
            acc = fmaf(xv.x, W1[(4 * k4 + 0) * H_DIM + lane], acc);
            acc = fmaf(xv.y, W1[(4 * k4 + 1) * H_DIM + lane], acc);
            acc = fmaf(xv.z, W1[(4 * k4 + 2) * H_DIM + lane], acc);
            acc = fmaf(xv.w, W1[(4 * k4 + 3) * H_DIM + lane], acc);
        }
        atomicAdd(&B[(size_t)d * H_DIM + lane], acc);
    }
}

// compute channel `lane` of A[n] = score[n] * (relu(relu(x[n]@W1 + B[n] + b1)@W2 + b2)@W3)
// wave-uniform n; must be called by all 64 lanes.
__device__ __forceinline__ float computeA(int n, int lane,
                                          const float* __restrict__ x,
                                          const float* __restrict__ B,
                                          const float* __restrict__ sc,
                                          const float* __restrict__ W1, float b1l,
                                          const float* __restrict__ W2, float b2l,
                                          const float* __restrict__ W3) {
    const float4* xr = (const float4*)(x + (size_t)n * C_IN);
    float u = 0.f;
    #pragma unroll 8
    for (int k4 = 0; k4 < C_IN / 4; ++k4) {
        float4 xv = xr[k4];
        u = fmaf(xv.x, W1[(4 * k4 + 0) * H_DIM + lane], u);
        u = fmaf(xv.y, W1[(4 * k4 + 1) * H_DIM + lane], u);
        u = fmaf(xv.z, W1[(4 * k4 + 2) * H_DIM + lane], u);
        u = fmaf(xv.w, W1[(4 * k4 + 3) * H_DIM + lane], u);
    }
    float t1 = fmaxf(u + B[(size_t)n * H_DIM + lane] + b1l, 0.f);
    float o1 = b2l;
    #pragma unroll 8
    for (int k = 0; k < H_DIM; ++k) o1 = fmaf(__shfl(t1, k, 64), W2[k * H_DIM + lane], o1);
    o1 = fmaxf(o1, 0.f);
    float v = 0.f;
    #pragma unroll 8
    for (int k = 0; k < H_DIM; ++k) v = fmaf(__shfl(o1, k, 64), W3[k * H_DIM + lane], v);
    return v * sc[n];
}

// ---------- merged finisher: 4 waves/graph compute A-vectors in parallel (LDS),
//            wave 0 then runs the bitwise-identical ascending-i finisher ----------
__global__ void kfin(const int* __restrict__ klist, const int* __restrict__ kcnt,
                     const float* __restrict__ sc, const float* __restrict__ x,
                     const float* __restrict__ W1, const float* __restrict__ b1,
                     const float* __restrict__ W2, const float* __restrict__ b2,
                     const float* __restrict__ W3, const float* __restrict__ b3,
                     const float* __restrict__ W4, const float* __restrict__ b4,
                     const float* __restrict__ Wl, const float* __restrict__ bl,
                     const float* __restrict__ B, const int* __restrict__ elsd,
                     const int* __restrict__ elcount, float* __restrict__ out) {
    __shared__ float Abuf[KPG][H_DIM];   // 8 KB: A-vectors for own kept nodes
    __shared__ float Gbuf[KPG][H_DIM];   // 8 KB: layer-2 aggregation per kept node
    __shared__ int   kl_s[KPG];
    const int g = blockIdx.x;
    const int t = threadIdx.x;           // 256 threads = 4 waves
    const int lane = t & 63;
    const int w = t >> 6;
    const float b1l = b1[lane], b2l = b2[lane];
    const int kc = kcnt[g];
    if (t < KPG) kl_s[t] = (t < kc) ? klist[g * KPG + t] : 0;
    __syncthreads();
    int ec = *elcount; if (ec > ELCAP) ec = ELCAP;
    // wave-parallel over kept nodes: A-vector + both-kept aggregation
    for (int i = w; i < kc; i += 4) {
        int n = __builtin_amdgcn_readfirstlane(kl_s[i]);
        float vA = computeA(n, lane, x, B, sc, W1, b1l, W2, b2l, W3);
        float agg = 0.f;
        for (int base = 0; base < ec; base += 64) {
            int idx = base + lane;
            int dd = (idx < ec) ? elsd[ELCAP + idx] : -1;
            bool mtc = (dd == n);
            int ssl = mtc ? elsd[idx] : 0;
            unsigned long long bal = __ballot(mtc);
            while (bal) {
                int j = __ffsll((long long)bal) - 1;
                bal &= bal - 1;
                int s = __builtin_amdgcn_readfirstlane(__shfl(ssl, j, 64));
                agg += computeA(s, lane, x, B, sc, W1, b1l, W2, b2l, W3);
            }
        }
        Abuf[i][lane] = vA;
        Gbuf[i][lane] = agg;
    }
    __syncthreads();
    if (w == 0) {   // ascending-i finisher: same summation order as passing k8f/k8c
        const float b3l = b3[lane], b4l = b4[lane];
        float gsum = 0.f;
        for (int i = 0; i < kc; ++i) {
            float tt = fmaxf(Abuf[i][lane] + Gbuf[i][lane] + b3l, 0.f);
            float o2 = b4l;
            #pragma unroll 8
            for (int k = 0; k < H_DIM; ++k)
                o2 = fmaf(__shfl(tt, k, 64), W4[k * H_DIM + lane], o2);
            gsum += fmaxf(o2, 0.f);
        }
        float p = gsum * Wl[lane];
        #pragma unroll
        for (int m = 32; m > 0; m >>= 1) p += __shfl_xor(p, m, 64);
        if (lane == 0) out[g] = p + bl[0];
    }
    if (g == 0 && w == 1) {
        int tot = 0;
        for (int i = lane; i < G_GRAPHS; i += 64) tot += kcnt[i];
        #pragma unroll
        for (int m = 32; m > 0; m >>= 1) tot += __shfl_xor(tot, m, 64);
        if (lane == 0) out[2 * G_GRAPHS] = (float)tot * (1.f / (float)N_NODES);
    }
}

extern "C" void kernel_launch(void* const* d_in, const int* in_sizes, int n_in,
                              void* d_out, int out_size, void* d_ws, size_t ws_size,
                              hipStream_t stream) {
    const float* x      = (const float*)d_in[0];
    const int*   ei     = (const int*)d_in[1];
    const int*   batch  = (const int*)d_in[2];
    const float* attn   = (const float*)d_in[3];
    const float* W1     = (const float*)d_in[4];
    const float* b1     = (const float*)d_in[5];
    const float* W2     = (const float*)d_in[6];
    const float* b2     = (const float*)d_in[7];
    const float* pool_w = (const float*)d_in[8];
    const float* W3     = (const float*)d_in[9];
    const float* b3     = (const float*)d_in[10];
    const float* W4     = (const float*)d_in[11];
    const float* b4     = (const float*)d_in[12];
    const float* Wl     = (const float*)d_in[13];
    const float* bl     = (const float*)d_in[14];
    float* out = (float*)d_out;

    // workspace layout
    float* B      = (float*)d_ws;                       // N*64 (kept rows only used)
    float* sc     = B + (size_t)N_NODES * H_DIM;        // N: kept scores only
    int*   klist  = (int*)(sc + N_NODES);               // G*KPG (per-graph strided)
    int*   kcnt   = klist + G_GRAPHS * KPG;             // G
    int*   elsd   = kcnt + G_GRAPHS;                    // 2*ELCAP
    unsigned int* kept_bits = (unsigned int*)(elsd + 2 * ELCAP);   // NBITS
    int*          elcount   = (int*)(kept_bits + NBITS);           // 1

    kSM   <<<G_GRAPHS, 1024, 0, stream>>>(x, batch, attn, pool_w, sc, kept_bits,
                                          klist, kcnt, B, elcount, out);
    kscan <<<(N_EDGES / 4 + 255) / 256, 256, 0, stream>>>(ei, kept_bits, x, W1, B,
                                                          elsd, elcount);
    kfin  <<<G_GRAPHS, 256, 0, stream>>>(klist, kcnt, sc, x, W1, b1, W2, b2, W3, b3,
                                         W4, b4, Wl, bl, B, elsd, elcount, out);
}